// Round 11
// baseline (575.222 us; speedup 1.0000x reference)
//
#include <hip/hip_runtime.h>

// MoE MLP (B=2,T=2048,H=1024,E=8,F=4096,K=2), fp32 in/out.
// route -> group tokens by expert -> RESIDENT-B grouped GEMMs: each block
// converts its fp32 weight panel ONCE into 128KB LDS (bf16, swizzled), then
// y-loops over the expert's 128-row tiles with only A staged per step
// (reg-staged, issue-early/write-late). G1: full-K panel, fused gelu.
// G2: k-window 512 (8 bf16 partial slices) -> combine sums slices + bias.

typedef unsigned short ushort_t;
typedef __attribute__((ext_vector_type(4))) unsigned int u32x4;
typedef __attribute__((ext_vector_type(4))) unsigned short u16x4;
typedef __attribute__((ext_vector_type(4))) float f32x4;
typedef __attribute__((ext_vector_type(8))) __bf16 bf16x8;

#define NTOK 4096   // B*T
#define HD   1024
#define FD   4096
#define NE   8
#define NKTOT 8192  // NTOK * TOP_K

__device__ __forceinline__ ushort_t f2bf(float f) {
  unsigned u = __builtin_bit_cast(unsigned, f);
  u += 0x7fffu + ((u >> 16) & 1u);   // RNE
  return (ushort_t)(u >> 16);
}
__device__ __forceinline__ float bf2f(ushort_t u) {
  unsigned v = ((unsigned)u) << 16;
  return __builtin_bit_cast(float, v);
}
__device__ __forceinline__ bf16x8 frag_ld(const void* p) {
  u32x4 v = *reinterpret_cast<const u32x4*>(p);
  return __builtin_bit_cast(bf16x8, v);
}

#define WAITVM0() asm volatile("s_waitcnt vmcnt(0)" ::: "memory")
#define BARRIER() do { asm volatile("s_waitcnt lgkmcnt(0)" ::: "memory");       \
                       __builtin_amdgcn_s_barrier(); } while (0)

// ---------------------------------------------------------------- init
__global__ void init_k(int* counts) {
  if (threadIdx.x < NE) counts[threadIdx.x] = 0;
}

// ------------------------------------------- router (+ fused x->bf16 conv)
__global__ void router_k(const float* __restrict__ x, const float* __restrict__ rw,
                         ushort_t* __restrict__ Xbf,
                         float* __restrict__ tokP, int* __restrict__ counts,
                         int* __restrict__ tk_e, int* __restrict__ tk_s,
                         float* __restrict__ tk_w) {
  const int w = threadIdx.x >> 6, l = threadIdx.x & 63;
  const int t = blockIdx.x * 4 + w;
  const float* xr = x + (size_t)t * HD;
  ushort_t* xo = Xbf + (size_t)t * HD;
  float acc[NE];
#pragma unroll
  for (int e = 0; e < NE; ++e) acc[e] = 0.f;
  for (int it = 0; it < HD / 64; ++it) {
    const int h = l + it * 64;
    const float xv = xr[h];
    xo[h] = f2bf(xv);
#pragma unroll
    for (int e = 0; e < NE; ++e) acc[e] = fmaf(xv, rw[e * HD + h], acc[e]);
  }
#pragma unroll
  for (int e = 0; e < NE; ++e) {
#pragma unroll
    for (int s = 32; s > 0; s >>= 1) acc[e] += __shfl_xor(acc[e], s, 64);
  }
  float m = acc[0];
#pragma unroll
  for (int e = 1; e < NE; ++e) m = fmaxf(m, acc[e]);
  float ssum = 0.f;
  float p[NE];
#pragma unroll
  for (int e = 0; e < NE; ++e) { p[e] = expf(acc[e] - m); ssum += p[e]; }
  const float inv = 1.f / ssum;
  if (l < NE) tokP[(size_t)t * NE + l] = p[l] * inv;

  if (l == 0) {
    int i0 = 0; float v0 = acc[0];
#pragma unroll
    for (int e = 1; e < NE; ++e) if (acc[e] > v0) { v0 = acc[e]; i0 = e; }
    int i1 = -1; float v1 = -3.4e38f;
#pragma unroll
    for (int e = 0; e < NE; ++e) if (e != i0 && acc[e] > v1) { v1 = acc[e]; i1 = e; }
    const float w0 = 1.f / (1.f + expf(v1 - v0));
    const int s0 = atomicAdd(&counts[i0], 1);
    const int s1 = atomicAdd(&counts[i1], 1);
    tk_e[2 * t] = i0;     tk_s[2 * t] = s0;     tk_w[2 * t] = w0;
    tk_e[2 * t + 1] = i1; tk_s[2 * t + 1] = s1; tk_w[2 * t + 1] = 1.f - w0;
  }
}

// ------------------------------------------- offsets + aux loss + tail out
__global__ void finalize_k(const float* __restrict__ tokP, const int* __restrict__ counts,
                           int* __restrict__ offsets, float* __restrict__ out_tail) {
  __shared__ float red[16][8];
  const int tid = threadIdx.x;  // 1024
  f32x4 a0 = {0.f, 0.f, 0.f, 0.f}, a1 = {0.f, 0.f, 0.f, 0.f};
#pragma unroll
  for (int k = 0; k < 4; ++k) {
    const float* p = tokP + ((size_t)tid * 4 + k) * 8;
    a0 += *reinterpret_cast<const f32x4*>(p);
    a1 += *reinterpret_cast<const f32x4*>(p + 4);
  }
#pragma unroll
  for (int s = 1; s < 64; s <<= 1) {
#pragma unroll
    for (int c = 0; c < 4; ++c) {
      a0[c] += __shfl_xor(a0[c], s, 64);
      a1[c] += __shfl_xor(a1[c], s, 64);
    }
  }
  if ((tid & 63) == 0) {
    const int wv = tid >> 6;
#pragma unroll
    for (int c = 0; c < 4; ++c) { red[wv][c] = a0[c]; red[wv][4 + c] = a1[c]; }
  }
  __syncthreads();
  if (tid == 0) {
    float P[8];
    for (int c = 0; c < 8; ++c) {
      float s = 0.f;
      for (int q = 0; q < 16; ++q) s += red[q][c];
      P[c] = s * (1.f / NTOK);
    }
    int off = 0; float aux = 0.f;
    for (int q = 0; q < NE; ++q) { offsets[q] = off; off += counts[q]; }
    for (int q = 0; q < NE; ++q) aux += ((float)counts[q] / (float)NKTOT) * P[q];
    out_tail[0] = (float)NE * aux;
    out_tail[1] = 0.f;
  }
}

// ---------------------------------------------------------------- slots
__global__ void build_slots_k(const int* __restrict__ tk_e, const int* __restrict__ tk_s,
                              const int* __restrict__ offsets, int* __restrict__ slot_token) {
  const int i = blockIdx.x * 256 + threadIdx.x;  // < NKTOT
  const int e = tk_e[i];
  slot_token[offsets[e] + tk_s[i]] = i >> 1;
}

// ---------------- RESIDENT-B grouped GEMM --------------------------------
// Block = (e, n-panel [, k-slice]); 256 thr = 4 waves (2M x 2N).
// Phase 1 (once): convert fp32 W panel -> Bs bf16 [n][KW] in LDS, swizzled
//   Bs[n*KW + ((k>>3)^(n&7))*8 + (k&7)]  (read side uses same key -> 2-way).
// Phase 2: for each 128-row tile of the expert: BK=64 steps; A reg-staged
//   (issue before compute, ds_write after barrier; swizzle slot^=(row&7)).
// G1 (NW=64, KW=1024): full-K panel; epilogue gelu+bias -> midb bf16.
// G2 (NW=128, KW=512): k-slice ks of 8; epilogue bf16 partial -> ybuf[ks].
template <bool IS_G1>
__global__ __launch_bounds__(256) void moe_resident(
    const ushort_t* __restrict__ A, const float* __restrict__ W,
    const float* __restrict__ bias,
    const int* __restrict__ counts, const int* __restrict__ offsets,
    const int* __restrict__ slot_token,
    ushort_t* __restrict__ midout, ushort_t* __restrict__ ybuf) {
  constexpr int KDF = IS_G1 ? HD : FD;     // A row stride (elems)
  constexpr int WST = IS_G1 ? FD : HD;     // W row stride (floats)
  constexpr int NW  = IS_G1 ? 64 : 128;    // panel n-width
  constexpr int KW  = IS_G1 ? 1024 : 512;  // panel K window
  constexpr int NSTEP = KW / 64;
  constexpr int NF = IS_G1 ? 2 : 4;        // B frags per wave (wave n = NW/2)
  const int id = blockIdx.x;
  const int e = id & 7;                    // XCD pin
  const int q = id >> 3;
  const int np = IS_G1 ? q : (q & 7);
  const int ks = IS_G1 ? 0 : (q >> 3);     // 0..7
  const int n0 = np * NW;
  const int KB = ks * KW;
  const int cnt = counts[e];
  const int off = offsets[e];
  const int nty = (cnt + 127) >> 7;

  __shared__ __align__(16) ushort_t Bs[NW * KW];   // 128 KB resident panel
  __shared__ __align__(16) ushort_t As[8192];      // 16 KB A tile / epi scratch

  const int tid = threadIdx.x;

  // ---------------- phase 1: convert fp32 panel -> Bs (once) --------------
  {
    constexpr int TPR = NW / 4;            // threads per k-row (16 / 32)
    constexpr int RPP = 256 / TPR;         // k-rows per pass (16 / 8)
    const int kr = tid / TPR;
    const int nc = (tid % TPR) * 4;
    const float* src = W + (size_t)e * ((size_t)HD * FD) +
                       (size_t)(KB + kr) * WST + n0 + nc;
    f32x4 R[8];
    for (int g = 0; g < KW / RPP; g += 8) {
#pragma unroll
      for (int j = 0; j < 8; ++j)
        R[j] = *reinterpret_cast<const f32x4*>(src + (size_t)(g + j) * RPP * WST);
#pragma unroll
      for (int j = 0; j < 8; ++j) {
        const int k = (g + j) * RPP + kr;  // k within panel
#pragma unroll
        for (int c = 0; c < 4; ++c) {
          const int n = nc + c;
          Bs[n * KW + (((k >> 3) ^ (n & 7)) << 3) + (k & 7)] = f2bf(R[j][c]);
        }
      }
    }
  }
  BARRIER();

  // ---------------- phase 2: y-loop over row tiles ------------------------
  const int w = tid >> 6, l = tid & 63;
  const int wr = w >> 1, wc = w & 1;       // 2M x 2N waves
  const int key = l & 7;

  f32x4 acc[4][NF];
  u32x4 RA[4];

  auto writeA = [&]() {
#pragma unroll
    for (int c = 0; c < 4; ++c) {
      const int row = c * 32 + w * 8 + (l >> 3);
      *reinterpret_cast<u32x4*>(&As[row * 64 + (((l & 7) ^ (row & 7)) << 3)]) = RA[c];
    }
  };

  for (int ty = 0; ty < nty; ++ty) {
    const int pos0 = off + ty * 128;
    const int rr = cnt - ty * 128;
    const int rows_rem = rr < 128 ? rr : 128;

    const char* ab[4];
#pragma unroll
    for (int c = 0; c < 4; ++c) {
      const int row = c * 32 + w * 8 + (l >> 3);
      int pos = pos0 + row; if (pos > NKTOT - 1) pos = NKTOT - 1;
      const size_t ar = IS_G1 ? (size_t)slot_token[pos] : (size_t)pos;
      ab[c] = (const char*)A + (ar * KDF + KB) * 2 + (l & 7) * 16;
    }
#pragma unroll
    for (int mm = 0; mm < 4; ++mm)
#pragma unroll
      for (int nn = 0; nn < NF; ++nn) acc[mm][nn] = f32x4{0.f, 0.f, 0.f, 0.f};

    // prologue: tile 0 into As
#pragma unroll
    for (int c = 0; c < 4; ++c) RA[c] = *reinterpret_cast<const u32x4*>(ab[c]);
    WAITVM0();
    writeA();
    BARRIER();

    for (int t = 0; t < NSTEP; ++t) {
      if (t + 1 < NSTEP) {
#pragma unroll
        for (int c = 0; c < 4; ++c)
          RA[c] = *reinterpret_cast<const u32x4*>(ab[c] + (t + 1) * 128);
      }
      __builtin_amdgcn_sched_barrier(0);   // keep loads ahead of compute
      // ---- compute step t
      {
        const int arow = wr * 64 + (l & 15);
        const int brow = wc * (NW / 2) + (l & 15);
#pragma unroll
        for (int kk = 0; kk < 2; ++kk) {
          const int kcA = kk * 4 + (l >> 4);
          const int kcB = t * 8 + kcA;
          bf16x8 afr[4];
#pragma unroll
          for (int mm = 0; mm < 4; ++mm)
            afr[mm] = frag_ld(&As[(arow + mm * 16) * 64 + ((kcA ^ key) << 3)]);
          __builtin_amdgcn_s_setprio(1);
#pragma unroll
          for (int nn = 0; nn < NF; ++nn) {
            const bf16x8 bfr =
                frag_ld(&Bs[(brow + nn * 16) * KW + ((kcB ^ key) << 3)]);
#pragma unroll
            for (int mm = 0; mm < 4; ++mm)
              acc[mm][nn] = __builtin_amdgcn_mfma_f32_16x16x32_bf16(
                  afr[mm], bfr, acc[mm][nn], 0, 0, 0);
          }
          __builtin_amdgcn_s_setprio(0);
        }
      }
      __builtin_amdgcn_s_barrier();        // all waves done reading As
      if (t + 1 < NSTEP) { WAITVM0(); writeA(); }
      BARRIER();                           // As(t+1) visible everywhere
    }

    // ---- epilogue (C/D: col=l&15, row=4*(l>>4)+j per 16x16 frag)
    const int lr4 = (l >> 4) * 4, lc = l & 15;
    if (IS_G1) {
#pragma unroll
      for (int nn = 0; nn < NF; ++nn) {
        const int col = wc * 32 + nn * 16 + lc;
        const float bv = bias[(size_t)e * FD + n0 + col];
#pragma unroll
        for (int mm = 0; mm < 4; ++mm) {
          const int rb = wr * 64 + mm * 16 + lr4;
#pragma unroll
          for (int j = 0; j < 4; ++j) {
            float v = acc[mm][nn][j] + bv;
            v = 0.5f * v * (1.0f + erff(v * 0.70710678118654752f));
            As[(rb + j) * 64 + col] = f2bf(v);
          }
        }
      }
      BARRIER();
#pragma unroll
      for (int p = 0; p < 4; ++p) {
        const int idx = p * 2048 + tid * 8;
        const int row = idx >> 6, col = idx & 63;
        if (row < rows_rem)
          *reinterpret_cast<u32x4*>(&midout[(size_t)(pos0 + row) * FD + n0 + col]) =
              *reinterpret_cast<const u32x4*>(&As[idx]);
      }
      BARRIER();
    } else {
#pragma unroll
      for (int h = 0; h < 2; ++h) {
        if (wr == h) {
#pragma unroll
          for (int nn = 0; nn < 4; ++nn) {
            const int col = wc * 64 + nn * 16 + lc;
#pragma unroll
            for (int mm = 0; mm < 4; ++mm) {
              const int rbl = mm * 16 + lr4;   // local row within half
#pragma unroll
              for (int j = 0; j < 4; ++j)
                As[(rbl + j) * 128 + col] = f2bf(acc[mm][nn][j]);
            }
          }
        }
        BARRIER();
#pragma unroll
        for (int p = 0; p < 4; ++p) {
          const int idx = p * 2048 + tid * 8;
          const int rowl = idx >> 7, col = idx & 127;
          const int row = h * 64 + rowl;
          if (row < rows_rem)
            *reinterpret_cast<u32x4*>(
                &ybuf[((size_t)ks * NKTOT + pos0 + row) * HD + n0 + col]) =
                *reinterpret_cast<const u32x4*>(&As[idx]);
        }
        BARRIER();
      }
    }
  }
}

// ---------------------------------------------------------------- combine
__global__ void combine_k(const ushort_t* __restrict__ ybuf, const int* __restrict__ tk_e,
                          const int* __restrict__ tk_s, const float* __restrict__ tk_w,
                          const int* __restrict__ offsets, const float* __restrict__ b2,
                          float* __restrict__ out) {
  const int t = blockIdx.x;
  const int e0 = tk_e[2 * t], e1 = tk_e[2 * t + 1];
  const size_t p0 = (size_t)offsets[e0] + tk_s[2 * t];
  const size_t p1 = (size_t)offsets[e1] + tk_s[2 * t + 1];
  const float w0 = tk_w[2 * t], w1v = tk_w[2 * t + 1];
  const int h = threadIdx.x * 4;
  f32x4 s0 = *reinterpret_cast<const f32x4*>(b2 + (size_t)e0 * HD + h);
  f32x4 s1 = *reinterpret_cast<const f32x4*>(b2 + (size_t)e1 * HD + h);
#pragma unroll
  for (int ks = 0; ks < 8; ++ks) {
    const u16x4 a = *reinterpret_cast<const u16x4*>(
        &ybuf[((size_t)ks * NKTOT + p0) * HD + h]);
    const u16x4 b = *reinterpret_cast<const u16x4*>(
        &ybuf[((size_t)ks * NKTOT + p1) * HD + h]);
    s0.x += bf2f(a.x); s0.y += bf2f(a.y); s0.z += bf2f(a.z); s0.w += bf2f(a.w);
    s1.x += bf2f(b.x); s1.y += bf2f(b.y); s1.z += bf2f(b.z); s1.w += bf2f(b.w);
  }
  f32x4 o = s0 * w0 + s1 * w1v;
  *reinterpret_cast<f32x4*>(out + (size_t)t * HD + h) = o;
}

// ---------------------------------------------------------------- launch
extern "C" void kernel_launch(void* const* d_in, const int* in_sizes, int n_in,
                              void* d_out, int out_size, void* d_ws, size_t ws_size,
                              hipStream_t stream) {
  const float* x  = (const float*)d_in[0];
  const float* rw = (const float*)d_in[1];
  const float* w1 = (const float*)d_in[2];
  const float* b1 = (const float*)d_in[3];
  const float* w2 = (const float*)d_in[4];
  const float* b2 = (const float*)d_in[5];
  float* out = (float*)d_out;

  char* ws = (char*)d_ws;
  ushort_t* Xbf  = (ushort_t*)(ws + 0);            //   8,388,608
  ushort_t* midb = (ushort_t*)(ws + 8388608);      //  67,108,864  [NKTOT][F] bf16
  ushort_t* ybuf = (ushort_t*)(ws + 75497472);     // 134,217,728  [8][NKTOT][H] bf16
  char* sm = ws + 209715200;
  int*   counts  = (int*)(sm);
  int*   offsets = (int*)(sm + 64);
  float* tokP    = (float*)(sm + 128);             // [NTOK][NE]
  int*   tk_e    = (int*)(sm + 128 + 131072);
  int*   tk_s    = (int*)(sm + 128 + 131072 + 32768);
  float* tk_w    = (float*)(sm + 128 + 131072 + 65536);
  int*   slot_token = (int*)(sm + 128 + 131072 + 98304);

  init_k<<<1, 64, 0, stream>>>(counts);
  router_k<<<1024, 256, 0, stream>>>(x, rw, Xbf, tokP, counts, tk_e, tk_s, tk_w);
  finalize_k<<<1, 1024, 0, stream>>>(tokP, counts, offsets, out + (size_t)NTOK * HD);
  build_slots_k<<<32, 256, 0, stream>>>(tk_e, tk_s, offsets, slot_token);
  // G1: e(8) x np(64) = 512 blocks, full-K resident panels
  moe_resident<true><<<512, 256, 0, stream>>>(
      Xbf, w1, b1, counts, offsets, slot_token, midb, (ushort_t*)nullptr);
  // G2: e(8) x [np(8) x ks(8)] = 512 blocks, k-window 512 partials
  moe_resident<false><<<512, 256, 0, stream>>>(
      midb, w2, b2, counts, offsets, slot_token, (ushort_t*)nullptr, ybuf);
  combine_k<<<4096, 256, 0, stream>>>(ybuf, tk_e, tk_s, tk_w, offsets, b2, out);
}

// Round 12
// 418.529 us; speedup vs baseline: 1.3744x; 1.3744x over previous
//
#include <hip/hip_runtime.h>

// MoE MLP (B=2,T=2048,H=1024,E=8,F=4096,K=2), fp32 in/out.
// route -> group tokens by expert -> fused grouped GEMMs (128x128 tile,
// 4 waves, BK=64, 48KB LDS -> 3 blocks/CU for barrier-group TLP; r8-proven
// issue-early/write-late schedule with counted vmcnt; fp32 weights streamed
// once, bf16 convert in-register) -> weighted combine.
// G2 = split-K2 with bf16 partials.

typedef unsigned short ushort_t;
typedef __attribute__((ext_vector_type(2))) float f32x2;
typedef __attribute__((ext_vector_type(4))) unsigned int u32x4;
typedef __attribute__((ext_vector_type(4))) unsigned short u16x4;
typedef __attribute__((ext_vector_type(4))) float f32x4;
typedef __attribute__((ext_vector_type(8))) __bf16 bf16x8;

#define NTOK 4096   // B*T
#define HD   1024
#define FD   4096
#define NE   8
#define NKTOT 8192  // NTOK * TOP_K

__device__ __forceinline__ ushort_t f2bf(float f) {
  unsigned u = __builtin_bit_cast(unsigned, f);
  u += 0x7fffu + ((u >> 16) & 1u);   // RNE
  return (ushort_t)(u >> 16);
}
__device__ __forceinline__ unsigned pk2(float a, float b) {
  unsigned r;
  asm("v_cvt_pk_bf16_f32 %0, %1, %2" : "=v"(r) : "v"(a), "v"(b));
  return r;  // lo = bf16(a), hi = bf16(b), RNE
}
__device__ __forceinline__ float bf2f(ushort_t u) {
  unsigned v = ((unsigned)u) << 16;
  return __builtin_bit_cast(float, v);
}
__device__ __forceinline__ bf16x8 frag_ld(const void* p) {
  u32x4 v = *reinterpret_cast<const u32x4*>(p);
  return __builtin_bit_cast(bf16x8, v);
}

#define GLOAD16(g, l) __builtin_amdgcn_global_load_lds(                         \
    (const __attribute__((address_space(1))) unsigned int*)(g),                 \
    (__attribute__((address_space(3))) unsigned int*)(l), 16, 0, 0)

#define WAITVM4()  asm volatile("s_waitcnt vmcnt(4)" ::: "memory")
#define WAITVM0()  asm volatile("s_waitcnt vmcnt(0)" ::: "memory")
#define BARRIER() do { asm volatile("s_waitcnt lgkmcnt(0)" ::: "memory");       \
                       __builtin_amdgcn_s_barrier(); } while (0)

// ---------------------------------------------------------------- init
__global__ void init_k(int* counts) {
  if (threadIdx.x < NE) counts[threadIdx.x] = 0;
}

// ------------------------------------------- router (+ fused x->bf16 conv)
__global__ void router_k(const float* __restrict__ x, const float* __restrict__ rw,
                         ushort_t* __restrict__ Xbf,
                         float* __restrict__ tokP, int* __restrict__ counts,
                         int* __restrict__ tk_e, int* __restrict__ tk_s,
                         float* __restrict__ tk_w) {
  const int w = threadIdx.x >> 6, l = threadIdx.x & 63;
  const int t = blockIdx.x * 4 + w;
  const float* xr = x + (size_t)t * HD;
  ushort_t* xo = Xbf + (size_t)t * HD;
  float acc[NE];
#pragma unroll
  for (int e = 0; e < NE; ++e) acc[e] = 0.f;
  for (int it = 0; it < HD / 64; ++it) {
    const int h = l + it * 64;
    const float xv = xr[h];
    xo[h] = f2bf(xv);
#pragma unroll
    for (int e = 0; e < NE; ++e) acc[e] = fmaf(xv, rw[e * HD + h], acc[e]);
  }
#pragma unroll
  for (int e = 0; e < NE; ++e) {
#pragma unroll
    for (int s = 32; s > 0; s >>= 1) acc[e] += __shfl_xor(acc[e], s, 64);
  }
  float m = acc[0];
#pragma unroll
  for (int e = 1; e < NE; ++e) m = fmaxf(m, acc[e]);
  float ssum = 0.f;
  float p[NE];
#pragma unroll
  for (int e = 0; e < NE; ++e) { p[e] = expf(acc[e] - m); ssum += p[e]; }
  const float inv = 1.f / ssum;
  if (l < NE) tokP[(size_t)t * NE + l] = p[l] * inv;

  if (l == 0) {
    int i0 = 0; float v0 = acc[0];
#pragma unroll
    for (int e = 1; e < NE; ++e) if (acc[e] > v0) { v0 = acc[e]; i0 = e; }
    int i1 = -1; float v1 = -3.4e38f;
#pragma unroll
    for (int e = 0; e < NE; ++e) if (e != i0 && acc[e] > v1) { v1 = acc[e]; i1 = e; }
    const float w0 = 1.f / (1.f + expf(v1 - v0));
    const int s0 = atomicAdd(&counts[i0], 1);
    const int s1 = atomicAdd(&counts[i1], 1);
    tk_e[2 * t] = i0;     tk_s[2 * t] = s0;     tk_w[2 * t] = w0;
    tk_e[2 * t + 1] = i1; tk_s[2 * t + 1] = s1; tk_w[2 * t + 1] = 1.f - w0;
  }
}

// ------------------------------------------- offsets + aux loss + tail out
__global__ void finalize_k(const float* __restrict__ tokP, const int* __restrict__ counts,
                           int* __restrict__ offsets, float* __restrict__ out_tail) {
  __shared__ float red[16][8];
  const int tid = threadIdx.x;  // 1024
  f32x4 a0 = {0.f, 0.f, 0.f, 0.f}, a1 = {0.f, 0.f, 0.f, 0.f};
#pragma unroll
  for (int k = 0; k < 4; ++k) {
    const float* p = tokP + ((size_t)tid * 4 + k) * 8;
    a0 += *reinterpret_cast<const f32x4*>(p);
    a1 += *reinterpret_cast<const f32x4*>(p + 4);
  }
#pragma unroll
  for (int s = 1; s < 64; s <<= 1) {
#pragma unroll
    for (int c = 0; c < 4; ++c) {
      a0[c] += __shfl_xor(a0[c], s, 64);
      a1[c] += __shfl_xor(a1[c], s, 64);
    }
  }
  if ((tid & 63) == 0) {
    const int wv = tid >> 6;
#pragma unroll
    for (int c = 0; c < 4; ++c) { red[wv][c] = a0[c]; red[wv][4 + c] = a1[c]; }
  }
  __syncthreads();
  if (tid == 0) {
    float P[8];
    for (int c = 0; c < 8; ++c) {
      float s = 0.f;
      for (int q = 0; q < 16; ++q) s += red[q][c];
      P[c] = s * (1.f / NTOK);
    }
    int off = 0; float aux = 0.f;
    for (int q = 0; q < NE; ++q) { offsets[q] = off; off += counts[q]; }
    for (int q = 0; q < NE; ++q) aux += ((float)counts[q] / (float)NKTOT) * P[q];
    out_tail[0] = (float)NE * aux;
    out_tail[1] = 0.f;
  }
}

// ---------------------------------------------------------------- slots
__global__ void build_slots_k(const int* __restrict__ tk_e, const int* __restrict__ tk_s,
                              const int* __restrict__ offsets, int* __restrict__ slot_token) {
  const int i = blockIdx.x * 256 + threadIdx.x;  // < NKTOT
  const int e = tk_e[i];
  slot_token[offsets[e] + tk_s[i]] = i >> 1;
}

// ------ fused grouped GEMM: 128x128 tile, 4 waves, 3 blocks/CU -------------
// 256 thr = 4 waves (2M x 2N, 64x64 each).  LDS 48KB:
//   As[2][128r][64k] bf16 (2x16KB dbuf): gload_lds, chunk swizzle
//     slot' = slot ^ (row&7) via pre-swizzled global src (r5-r10 proven).
//   Bs[128n][64k] bf16 (16KB single): slot' = chunk ^ ((n>>1)&7) (r7/r10
//     proven conflict-free both sides).
// Per step t (r8-proven order): issueB(t+1)->regs (16 f32x2, lane owns
// n={2l,2l+1}, k=16w..16w+15); stageA(t+1)->As[(t+1)&1] (4 gload_lds);
// compute(t); s_barrier (Bs free); vmcnt(4) [B(t+1) landed]; cvt+writeB;
// vmcnt(0) [A(t+1) landed]; barrier.  3 barrier-groups/CU cover the
// exposed load latency (m97's mechanism).
// G1: mid = gelu(X@w1+b1) bf16.  G2: bf16 k-slice partials (ks=2, K=2048).
template <bool IS_G1>
__global__ __launch_bounds__(256, 3) void moe_fused(
    const ushort_t* __restrict__ A, const float* __restrict__ W,
    const float* __restrict__ bias,
    const int* __restrict__ counts, const int* __restrict__ offsets,
    const int* __restrict__ slot_token,
    ushort_t* __restrict__ midout, ushort_t* __restrict__ ybuf) {
  constexpr int KDF = IS_G1 ? HD : FD;   // A row stride (elems)
  constexpr int WST = IS_G1 ? FD : HD;   // W row stride (floats)
  constexpr int NSTEP = IS_G1 ? 16 : 32;
  const int id = blockIdx.x;
  const int e = id & 7;                  // XCD pin
  const int q = id >> 3;
  const int ty = q % 10;
  const int r = q / 10;
  const int np = IS_G1 ? r : (r >> 1);
  const int ks = IS_G1 ? 0 : (r & 1);
  const int n0 = np * 128;
  const int KB = ks * 2048;              // k window base (elems)
  const int cnt = counts[e];
  if (ty * 128 >= cnt) return;
  const int off = offsets[e];
  const int pos0 = off + ty * 128;
  const int rr = cnt - ty * 128;
  const int rows_rem = rr < 128 ? rr : 128;

  // ushort idx: As[0]=0..8191, As[1]=8192..16383, Bs=16384..24575 (48KB)
  __shared__ __align__(16) ushort_t lds[24576];

  const int tid = threadIdx.x;
  const int w = tid >> 6, l = tid & 63;
  const int wr = w >> 1, wc = w & 1;     // 2 (M) x 2 (N) waves, 64x64 each

  // ---- A staging (pre-swizzled source, linear LDS dest)
  const int sw = (((l & 7) ^ ((l >> 3) & 7)) << 4);
  const char* ab[4];
#pragma unroll
  for (int c = 0; c < 4; ++c) {
    const int row = c * 32 + w * 8 + (l >> 3);
    int pos = pos0 + row; if (pos > NKTOT - 1) pos = NKTOT - 1;
    const size_t ar = IS_G1 ? (size_t)slot_token[pos] : (size_t)pos;
    ab[c] = (const char*)A + (ar * KDF + KB) * 2 + sw;
  }

  // ---- B source: lane owns n cols {2l, 2l+1}, k rows 16w .. 16w+15
  const float* wB = W + (size_t)e * ((size_t)HD * FD) +
                    ((size_t)KB + 16 * w) * WST + n0 + 2 * l;

  f32x4 acc[4][4] = {};
  f32x2 R[16];

  auto stageA = [&](int tt) {
    ushort_t* base = &lds[(tt & 1) * 8192];
#pragma unroll
    for (int c = 0; c < 4; ++c)
      GLOAD16(ab[c] + tt * 128, base + (c * 32 + w * 8) * 64);
  };
  auto issueB = [&](int tt) {
    const float* p = wB + (size_t)tt * 64 * WST;
#pragma unroll
    for (int i = 0; i < 16; ++i)
      R[i] = *reinterpret_cast<const f32x2*>(p + (size_t)i * WST);
  };
  auto writeB = [&]() {
    // rows n=2l, 2l+1; k-chunks 2w, 2w+1; slot = chunk ^ ((n>>1)&7) = ^ (l&7)
    const int key = l & 7;
    ushort_t* d = &lds[16384 + (2 * l) * 64];
    u32x4 v;
    v.x = pk2(R[0].x, R[1].x);   v.y = pk2(R[2].x, R[3].x);
    v.z = pk2(R[4].x, R[5].x);   v.w = pk2(R[6].x, R[7].x);
    *reinterpret_cast<u32x4*>(d + (((2 * w) ^ key) << 3)) = v;
    v.x = pk2(R[8].x, R[9].x);   v.y = pk2(R[10].x, R[11].x);
    v.z = pk2(R[12].x, R[13].x); v.w = pk2(R[14].x, R[15].x);
    *reinterpret_cast<u32x4*>(d + (((2 * w + 1) ^ key) << 3)) = v;
    ushort_t* d2 = d + 64;
    v.x = pk2(R[0].y, R[1].y);   v.y = pk2(R[2].y, R[3].y);
    v.z = pk2(R[4].y, R[5].y);   v.w = pk2(R[6].y, R[7].y);
    *reinterpret_cast<u32x4*>(d2 + (((2 * w) ^ key) << 3)) = v;
    v.x = pk2(R[8].y, R[9].y);   v.y = pk2(R[10].y, R[11].y);
    v.z = pk2(R[12].y, R[13].y); v.w = pk2(R[14].y, R[15].y);
    *reinterpret_cast<u32x4*>(d2 + (((2 * w + 1) ^ key) << 3)) = v;
  };
  auto compute = [&](int tt) {
    const ushort_t* Ab = &lds[(tt & 1) * 8192];
    const ushort_t* Bb = &lds[16384];
    const int arow = wr * 64 + (l & 15);
    const int brow = wc * 64 + (l & 15);
    const int ax = l & 7;
    const int bx = (l >> 1) & 7;
#pragma unroll
    for (int kk = 0; kk < 2; ++kk) {
      const int kc = kk * 4 + (l >> 4);
      bf16x8 afr[4];
#pragma unroll
      for (int mm = 0; mm < 4; ++mm)
        afr[mm] = frag_ld(&Ab[(arow + mm * 16) * 64 + ((kc ^ ax) << 3)]);
      __builtin_amdgcn_s_setprio(1);
#pragma unroll
      for (int nn = 0; nn < 4; ++nn) {
        const bf16x8 bfr = frag_ld(&Bb[(brow + nn * 16) * 64 + ((kc ^ bx) << 3)]);
#pragma unroll
        for (int mm = 0; mm < 4; ++mm)
          acc[mm][nn] = __builtin_amdgcn_mfma_f32_16x16x32_bf16(
              afr[mm], bfr, acc[mm][nn], 0, 0, 0);
      }
      __builtin_amdgcn_s_setprio(0);
    }
  };

  // ---- prologue: B(0)+A(0); vmcnt(4) drains B(0); write; drain A(0); barrier.
  issueB(0);
  stageA(0);
  WAITVM4();
  writeB();
  WAITVM0();
  BARRIER();

  // ---- main loop: issue-early / write-late (r8-proven order)
  for (int t = 0; t < NSTEP - 1; ++t) {
    issueB(t + 1);
    stageA(t + 1);
    __builtin_amdgcn_sched_barrier(0);   // keep issues ahead of compute
    compute(t);
    __builtin_amdgcn_s_barrier();        // all waves done reading Bs
    WAITVM4();                           // B(t+1) regs landed (issued first)
    writeB();
    WAITVM0();                           // this wave's A(t+1) landed
    BARRIER();                           // As/Bs(t+1) ready everywhere
  }
  compute(NSTEP - 1);
  __builtin_amdgcn_s_barrier();          // all compute done before repack

  // ---- epilogue: acc -> bf16 via LDS repack, coalesced 16B row stores.
  // C/D: col = l&15, row = 4*(l>>4)+j within each 16x16 frag.
  {
    const int lr4 = (l >> 4) * 4, lc = l & 15;
#pragma unroll
    for (int nn = 0; nn < 4; ++nn) {
      const int col = wc * 64 + nn * 16 + lc;
      const float bv = IS_G1 ? bias[(size_t)e * FD + n0 + col] : 0.f;
#pragma unroll
      for (int mm = 0; mm < 4; ++mm) {
        const int rb = wr * 64 + mm * 16 + lr4;
#pragma unroll
        for (int j = 0; j < 4; ++j) {
          float v = acc[mm][nn][j] + bv;
          if (IS_G1) v = 0.5f * v * (1.0f + erff(v * 0.70710678118654752f));
          lds[(rb + j) * 128 + col] = f2bf(v);
        }
      }
    }
    BARRIER();
#pragma unroll
    for (int p = 0; p < 8; ++p) {
      const int idx = p * 2048 + tid * 8;
      const int row = idx >> 7;
      const int col = idx & 127;
      if (row < rows_rem) {
        const u32x4 v = *reinterpret_cast<const u32x4*>(&lds[idx]);
        if (IS_G1)
          *reinterpret_cast<u32x4*>(&midout[(size_t)(pos0 + row) * FD + n0 + col]) = v;
        else
          *reinterpret_cast<u32x4*>(
              &ybuf[((size_t)ks * NKTOT + pos0 + row) * HD + n0 + col]) = v;
      }
    }
  }
}

// ---------------------------------------------------------------- combine
__global__ void combine_k(const ushort_t* __restrict__ ybuf, const int* __restrict__ tk_e,
                          const int* __restrict__ tk_s, const float* __restrict__ tk_w,
                          const int* __restrict__ offsets, const float* __restrict__ b2,
                          float* __restrict__ out) {
  const int t = blockIdx.x;
  const int e0 = tk_e[2 * t], e1 = tk_e[2 * t + 1];
  const size_t p0 = (size_t)offsets[e0] + tk_s[2 * t];
  const size_t p1 = (size_t)offsets[e1] + tk_s[2 * t + 1];
  const float w0 = tk_w[2 * t], w1v = tk_w[2 * t + 1];
  const int h = threadIdx.x * 4;
  f32x4 s0 = *reinterpret_cast<const f32x4*>(b2 + (size_t)e0 * HD + h);
  f32x4 s1 = *reinterpret_cast<const f32x4*>(b2 + (size_t)e1 * HD + h);
#pragma unroll
  for (int ks = 0; ks < 2; ++ks) {
    const u16x4 a = *reinterpret_cast<const u16x4*>(
        &ybuf[((size_t)ks * NKTOT + p0) * HD + h]);
    const u16x4 b = *reinterpret_cast<const u16x4*>(
        &ybuf[((size_t)ks * NKTOT + p1) * HD + h]);
    s0.x += bf2f(a.x); s0.y += bf2f(a.y); s0.z += bf2f(a.z); s0.w += bf2f(a.w);
    s1.x += bf2f(b.x); s1.y += bf2f(b.y); s1.z += bf2f(b.z); s1.w += bf2f(b.w);
  }
  f32x4 o = s0 * w0 + s1 * w1v;
  *reinterpret_cast<f32x4*>(out + (size_t)t * HD + h) = o;
}

// ---------------------------------------------------------------- launch
extern "C" void kernel_launch(void* const* d_in, const int* in_sizes, int n_in,
                              void* d_out, int out_size, void* d_ws, size_t ws_size,
                              hipStream_t stream) {
  const float* x  = (const float*)d_in[0];
  const float* rw = (const float*)d_in[1];
  const float* w1 = (const float*)d_in[2];
  const float* b1 = (const float*)d_in[3];
  const float* w2 = (const float*)d_in[4];
  const float* b2 = (const float*)d_in[5];
  float* out = (float*)d_out;

  char* ws = (char*)d_ws;
  ushort_t* Xbf  = (ushort_t*)(ws + 0);            //   8,388,608
  ushort_t* midb = (ushort_t*)(ws + 8388608);      //  67,108,864  [NKTOT][F] bf16
  ushort_t* ybuf = (ushort_t*)(ws + 75497472);     //  33,554,432  [2][NKTOT][H] bf16
  char* sm = ws + 209715200;
  int*   counts  = (int*)(sm);
  int*   offsets = (int*)(sm + 64);
  float* tokP    = (float*)(sm + 128);             // [NTOK][NE]
  int*   tk_e    = (int*)(sm + 128 + 131072);
  int*   tk_s    = (int*)(sm + 128 + 131072 + 32768);
  float* tk_w    = (float*)(sm + 128 + 131072 + 65536);
  int*   slot_token = (int*)(sm + 128 + 131072 + 98304);

  init_k<<<1, 64, 0, stream>>>(counts);
  router_k<<<1024, 256, 0, stream>>>(x, rw, Xbf, tokP, counts, tk_e, tk_s, tk_w);
  finalize_k<<<1, 1024, 0, stream>>>(tokP, counts, offsets, out + (size_t)NTOK * HD);
  build_slots_k<<<32, 256, 0, stream>>>(tk_e, tk_s, offsets, slot_token);
  // G1 grid: e(8) x [np(32) x ty(10)] = 2560 blocks
  moe_fused<true><<<2560, 256, 0, stream>>>(
      Xbf, w1, b1, counts, offsets, slot_token, midb, (ushort_t*)nullptr);
  // G2 grid: e(8) x [np(8) x ks(2) x ty(10)] = 1280 blocks
  moe_fused<false><<<1280, 256, 0, stream>>>(
      midb, w2, b2, counts, offsets, slot_token, (ushort_t*)nullptr, ybuf);
  combine_k<<<4096, 256, 0, stream>>>(ybuf, tk_e, tk_s, tk_w, offsets, b2, out);
}